// Round 8
// baseline (3599.146 us; speedup 1.0000x reference)
//
#include <hip/hip_runtime.h>
#include <hip/hip_fp16.h>
#include <hip/hip_cooperative_groups.h>

namespace cg = cooperative_groups;

#define NUM_STEPS 5
typedef unsigned int u32;

// ---------------- fast path constants ----------------
#define RSH 10             // 1024 nodes per dst-bucket
#define RSZ 1024
#define SB  1024           // hist/scatter blocks (chunking MUST match between them)
#define HT  512            // hist threads
#define ST  512            // scatter threads
#define NBMAX 512          // max buckets supported by scatter LDS bins
#define BINS 8             // scatter bin slots (8 x 8B = 64B line)
#define SRC_BITS 19        // N=500000 < 2^19
#define SRC_MASK 0x7FFFFu

static inline size_t align256(size_t x){ return (x + 255) & ~(size_t)255; }

// ---------------- preprocessing kernels (proven round-5 protocol) ----------------

// per-block histogram of edge targets into B buckets (int4-vectorized)
__global__ void hist_kernel(const int* __restrict__ dst, long long E, int B,
                            u32* __restrict__ blk_cnt){
    extern __shared__ u32 hist[];
    int sb = blockIdx.x;
    long long E4 = E >> 2;
    long long chunk = (E4 + SB - 1)/SB;
    long long i0 = (long long)sb*chunk;
    long long i1 = i0 + chunk; if(i1 > E4) i1 = E4;
    for(int b=threadIdx.x; b<B; b+=blockDim.x) hist[b]=0;
    __syncthreads();
    const int4* d4 = (const int4*)dst;
    for(long long i=i0+threadIdx.x; i<i1; i+=blockDim.x){
        int4 d = d4[i];
        atomicAdd(&hist[((u32)d.x)>>RSH], 1u);
        atomicAdd(&hist[((u32)d.y)>>RSH], 1u);
        atomicAdd(&hist[((u32)d.z)>>RSH], 1u);
        atomicAdd(&hist[((u32)d.w)>>RSH], 1u);
    }
    if(sb==0){   // scalar tail (E % 4)
        for(long long e=(E4<<2)+threadIdx.x; e<E; e+=blockDim.x)
            atomicAdd(&hist[((u32)dst[e])>>RSH], 1u);
    }
    __syncthreads();
    for(int b=threadIdx.x; b<B; b+=blockDim.x) blk_cnt[(size_t)sb*B + b] = hist[b];
}

// per-bucket exclusive scan over the SB per-block counts (one block per bucket)
__global__ __launch_bounds__(SB) void
colscan_kernel(u32* __restrict__ blk_cnt, int B, u32* __restrict__ tot){
    __shared__ u32 s[SB];
    int b = blockIdx.x, t = threadIdx.x;   // blockDim.x == SB
    u32 v = blk_cnt[(size_t)t*B + b];
    s[t] = v; __syncthreads();
    for(int off=1; off<SB; off<<=1){
        u32 x = (t>=off) ? s[t-off] : 0;
        __syncthreads();
        s[t] += x;
        __syncthreads();
    }
    blk_cnt[(size_t)t*B + b] = s[t] - v;     // exclusive
    if(t==SB-1) tot[b] = s[SB-1];
}

// exclusive scan of bucket totals -> bucket base offsets (single block, B <= 512)
__global__ void basescan_kernel(const u32* __restrict__ tot, u32* __restrict__ base, int B){
    __shared__ u32 s[256];
    int t = threadIdx.x;
    u32 v0 = (2*t   < B) ? tot[2*t]   : 0;
    u32 v1 = (2*t+1 < B) ? tot[2*t+1] : 0;
    u32 sum = v0 + v1;
    s[t] = sum; __syncthreads();
    for(int off=1; off<256; off<<=1){
        u32 x = (t>=off) ? s[t-off] : 0;
        __syncthreads();
        s[t] += x;
        __syncthreads();
    }
    u32 run = s[t] - sum;
    if(2*t   < B) base[2*t]   = run;
    if(2*t+1 < B) base[2*t+1] = run + v0;
    if(t==255) base[B] = s[255];     // == E
}

// LDS-binned scatter into dst-bucket order: edges accumulate in per-bucket
// 64B bins and flush as full cache lines; overflow slots write directly.
__global__ __launch_bounds__(ST) void
scatter_kernel(const int* __restrict__ src, const int* __restrict__ dst,
               const float* __restrict__ ep, long long E, int B,
               const u32* __restrict__ blk_rel, const u32* __restrict__ base,
               uint2* __restrict__ edges){
    __shared__ uint2 bin[NBMAX][BINS];   // 32 KB
    __shared__ u32 cnt[NBMAX];
    __shared__ u32 gcur[NBMAX];
    const int sb = blockIdx.x, t = threadIdx.x;
    long long E4 = E >> 2;
    long long chunk = (E4 + SB - 1)/SB;
    long long i0 = (long long)sb*chunk;
    long long i1 = i0 + chunk; if(i1 > E4) i1 = E4;
    for(int b=t; b<B; b+=ST){ cnt[b]=0; gcur[b]=base[b]+blk_rel[(size_t)sb*B+b]; }
    __syncthreads();
    const int4*   s4=(const int4*)src;
    const int4*   d4=(const int4*)dst;
    const float4* w4=(const float4*)ep;
    for(long long it=i0; it<i1; it+=ST){
        long long i = it + t;
        bool valid = (i < i1);
        u32 bk[4]; u32 sl[4]; uint2 pl[4];
        if(valid){
            int4 s=s4[i]; int4 d=d4[i]; float4 w=w4[i];
            u32 dd;
            dd=(u32)d.x; bk[0]=dd>>RSH; pl[0]=make_uint2(((u32)s.x)|((dd&(RSZ-1))<<SRC_BITS), __float_as_uint(w.x));
            dd=(u32)d.y; bk[1]=dd>>RSH; pl[1]=make_uint2(((u32)s.y)|((dd&(RSZ-1))<<SRC_BITS), __float_as_uint(w.y));
            dd=(u32)d.z; bk[2]=dd>>RSH; pl[2]=make_uint2(((u32)s.z)|((dd&(RSZ-1))<<SRC_BITS), __float_as_uint(w.z));
            dd=(u32)d.w; bk[3]=dd>>RSH; pl[3]=make_uint2(((u32)s.w)|((dd&(RSZ-1))<<SRC_BITS), __float_as_uint(w.w));
            #pragma unroll
            for(int k=0;k<4;k++) sl[k]=atomicAdd(&cnt[bk[k]],1u);
        }
        __syncthreads();
        if(valid){
            #pragma unroll
            for(int k=0;k<4;k++){
                if(sl[k] < BINS) bin[bk[k]][sl[k]] = pl[k];
                else             edges[gcur[bk[k]] + sl[k]] = pl[k];
            }
        }
        __syncthreads();
        for(int b=t; b<B; b+=ST){
            u32 c = cnt[b];
            if(c >= BINS){
                u32 g = gcur[b];
                #pragma unroll
                for(int k2=0;k2<BINS;k2++) edges[g+k2] = bin[b][k2];
                gcur[b] = g + c;
                cnt[b]  = 0;
            }
        }
        __syncthreads();
    }
    if(sb==0){   // tail edges (E % 4)
        long long tb = E4<<2;
        int nt = (int)(E - tb);
        if(nt > 0){
            bool v = (t < nt);
            u32 bk0=0, sl0=0; uint2 pl0=make_uint2(0,0);
            if(v){
                u32 dd=(u32)dst[tb+t]; bk0=dd>>RSH;
                pl0=make_uint2(((u32)src[tb+t])|((dd&(RSZ-1))<<SRC_BITS), __float_as_uint(ep[tb+t]));
                sl0=atomicAdd(&cnt[bk0],1u);
            }
            __syncthreads();
            if(v){ if(sl0<BINS) bin[bk0][sl0]=pl0; else edges[gcur[bk0]+sl0]=pl0; }
            __syncthreads();
        }
    }
    for(int b=t; b<B; b+=ST){
        u32 c = cnt[b]; if(c > BINS) c = BINS;
        u32 g = gcur[b];
        for(u32 k2=0;k2<c;k2++) edges[g+k2] = bin[b][k2];
    }
}

// Persistent cooperative kernel: all 5 steps + node updates fused.
// One block per bucket (1024 nodes, 1024 threads, 1 node/thread); prod lives
// in a register; p (fp16) is the only cross-block state, republished per step.
__global__ __launch_bounds__(1024, 2) void
fused_steps(const uint2* __restrict__ edges, const u32* __restrict__ base,
            __half* __restrict__ p, const float* __restrict__ prior,
            float* __restrict__ out, int n){
    cg::grid_group grid = cg::this_grid();
    __shared__ float acc[2][RSZ];        // 8 KB, 2 replicas
    const int b = blockIdx.x, t = threadIdx.x;
    const int i = (b << RSH) + t;
    acc[0][t] = 0.0f; acc[1][t] = 0.0f;
    if(i < n) p[i] = __float2half_rn(prior[i]);   // init p (fused)
    float prodr = 1.0f;
    const u32 e0 = base[b], e1 = base[b+1];
    const int rep = t & 1;
    __threadfence();
    grid.sync();
    for(int step=0; step<NUM_STEPS; ++step){
        // edge phase: coalesced 8B stream + fp16 gather + LDS atomic
        for(u32 e = e0 + t; e < e1; e += 1024){
            uint2 pk = edges[e];
            atomicAdd(&acc[rep][pk.x >> SRC_BITS],
                      __uint_as_float(pk.y) * __half2float(p[pk.x & SRC_MASK]));
        }
        __threadfence();
        grid.sync();
        // node phase: each thread owns node i
        float a = acc[0][t] + acc[1][t];
        acc[0][t] = 0.0f; acc[1][t] = 0.0f;
        float np = prodr * (1.0f - expf(-a));
        prodr *= (1.0f - np);
        if(i < n) p[i] = __float2half_rn(np);
        __threadfence();
        grid.sync();
    }
    if(i < n) out[i] = 1.0f - prodr + prior[i];
}

// ---------------- fallback (round-1) kernels ----------------

__global__ void init_kernel(const float* __restrict__ prior, float* __restrict__ p,
                            float* __restrict__ prod, float* __restrict__ agg, int n){
    int i = blockIdx.x*blockDim.x + threadIdx.x;
    if(i<n){ p[i]=prior[i]; prod[i]=1.0f; agg[i]=0.0f; }
}

__global__ void edge_kernel(const int* __restrict__ src, const int* __restrict__ dst,
                            const float* __restrict__ ep, const float* __restrict__ p,
                            float* __restrict__ agg, int e4, int e_rem, long long e4base){
    int i = blockIdx.x*blockDim.x + threadIdx.x;
    if(i < e4){
        int4   s = ((const int4*)src)[i];
        int4   t = ((const int4*)dst)[i];
        float4 w = ((const float4*)ep)[i];
        atomicAdd(&agg[t.x], w.x * p[s.x]);
        atomicAdd(&agg[t.y], w.y * p[s.y]);
        atomicAdd(&agg[t.z], w.z * p[s.z]);
        atomicAdd(&agg[t.w], w.w * p[s.w]);
    }
    if(blockIdx.x==0 && threadIdx.x < e_rem){
        long long e = e4base + threadIdx.x;
        atomicAdd(&agg[dst[e]], ep[e]*p[src[e]]);
    }
}

__global__ void node_kernel(float* __restrict__ p, float* __restrict__ prod,
                            float* __restrict__ agg, const float* __restrict__ prior,
                            float* __restrict__ out, int n, int final_step){
    int i = blockIdx.x*blockDim.x + threadIdx.x;
    if(i<n){
        float a = agg[i]; agg[i]=0.0f;
        float pr_old = prod[i];
        float np = pr_old*(1.0f - expf(-a));
        float pr = pr_old*(1.0f - np);
        prod[i]=pr; p[i]=np;
        if(final_step) out[i] = 1.0f - pr + prior[i];
    }
}

// ---------------- launch ----------------

extern "C" void kernel_launch(void* const* d_in, const int* in_sizes, int n_in,
                              void* d_out, int out_size, void* d_ws, size_t ws_size,
                              hipStream_t stream){
    const float* prior = (const float*)d_in[0];
    const int*   eidx  = (const int*)d_in[1];
    const float* ep    = (const float*)d_in[2];

    const int n = in_sizes[0];
    const long long E = (long long)in_sizes[2];
    const int* src = eidx;
    const int* dst = eidx + E;
    float* out = (float*)d_out;

    const int B = (n + RSZ - 1) >> RSH;   // buckets (489 for n=500000)

    // ws layout
    size_t szNh  = align256((size_t)n * 2);              // fp16 p table
    size_t szB1  = align256((size_t)(B + 1) * 4);
    size_t szB   = align256((size_t)B * 4);
    size_t szCnt = align256((size_t)SB * B * 4);
    size_t szE2  = align256((size_t)E * 8);

    size_t off_p    = 0;
    size_t off_base = off_p + szNh;
    size_t off_tot  = off_base + szB1;
    size_t off_cnt  = off_tot + szB;
    size_t off_edge = off_cnt + szCnt;
    size_t need     = off_edge + szE2;

    char* ws = (char*)d_ws;

    if(ws_size >= need && n < (1 << SRC_BITS) && B <= NBMAX){
        __half* p    = (__half*)(ws + off_p);
        u32*    base = (u32*)   (ws + off_base);
        u32*    tot  = (u32*)   (ws + off_tot);
        u32*    cnt  = (u32*)   (ws + off_cnt);
        uint2*  edges= (uint2*) (ws + off_edge);

        hist_kernel<<<SB, HT, (size_t)B*4, stream>>>(dst, E, B, cnt);
        colscan_kernel<<<B, SB, 0, stream>>>(cnt, B, tot);
        basescan_kernel<<<1, 256, 0, stream>>>(tot, base, B);
        scatter_kernel<<<SB, ST, 0, stream>>>(src, dst, ep, E, B, cnt, base, edges);

        int n_arg = n;
        void* args[] = { (void*)&edges, (void*)&base, (void*)&p,
                         (void*)&prior, (void*)&out, (void*)&n_arg };
        hipLaunchCooperativeKernel((const void*)fused_steps,
                                   dim3(B), dim3(1024), args, 0, stream);
    } else {
        // fallback: global-atomic version (round 1)
        float* p    = (float*)d_ws;
        float* prod = p + n;
        float* agg  = prod + n;
        const int nb_n = (n + 255)/256;
        init_kernel<<<nb_n, 256, 0, stream>>>(prior, p, prod, agg, n);
        const int e4 = (int)(E/4);
        const int e_rem = (int)(E%4);
        const long long e4base = (long long)e4*4;
        const int nb_e = (e4 + 255)/256;
        for(int step=0; step<NUM_STEPS; ++step){
            edge_kernel<<<nb_e, 256, 0, stream>>>(src, dst, ep, p, agg, e4, e_rem, e4base);
            node_kernel<<<nb_n, 256, 0, stream>>>(p, prod, agg, prior, out, n,
                                                  step == NUM_STEPS-1 ? 1 : 0);
        }
    }
}

// Round 9
// 1486.622 us; speedup vs baseline: 2.4210x; 2.4210x over previous
//
#include <hip/hip_runtime.h>
#include <hip/hip_fp16.h>

#define NUM_STEPS 5
typedef unsigned int u32;

// ---------------- fast path constants ----------------
#define RSH 10             // 1024 nodes per dst-bucket
#define RSZ 1024
#define SB  1024           // hist/scatter blocks (chunking MUST match between them)
#define HT  512            // hist threads
#define ST  512            // scatter threads
#define NBMAX 512          // max buckets supported by scatter LDS bins
#define BINS 8             // bin slots (8 slots; 8B payload pass1, 4B payload pass2)
#define SRC_BITS 19        // N=500000 < 2^19
#define SRC_MASK 0x7FFFFu
#define QMAX 8191.0f       // 13-bit edge-prob quantization

static inline size_t align256(size_t x){ return (x + 255) & ~(size_t)255; }

// ---------------- preprocessing ----------------

__global__ void init_fast(const float* __restrict__ prior, __half* __restrict__ p0,
                          float* __restrict__ prod, int n){
    int i = blockIdx.x*blockDim.x + threadIdx.x;
    if(i<n){ p0[i]=__float2half_rn(prior[i]); prod[i]=1.0f; }
}

// per-block histogram of edge targets into B buckets (int4-vectorized)
__global__ void hist_kernel(const int* __restrict__ dst, long long E, int B,
                            u32* __restrict__ blk_cnt){
    extern __shared__ u32 hist[];
    int sb = blockIdx.x;
    long long E4 = E >> 2;
    long long chunk = (E4 + SB - 1)/SB;
    long long i0 = (long long)sb*chunk;
    long long i1 = i0 + chunk; if(i1 > E4) i1 = E4;
    for(int b=threadIdx.x; b<B; b+=blockDim.x) hist[b]=0;
    __syncthreads();
    const int4* d4 = (const int4*)dst;
    for(long long i=i0+threadIdx.x; i<i1; i+=blockDim.x){
        int4 d = d4[i];
        atomicAdd(&hist[((u32)d.x)>>RSH], 1u);
        atomicAdd(&hist[((u32)d.y)>>RSH], 1u);
        atomicAdd(&hist[((u32)d.z)>>RSH], 1u);
        atomicAdd(&hist[((u32)d.w)>>RSH], 1u);
    }
    if(sb==0){   // scalar tail (E % 4)
        for(long long e=(E4<<2)+threadIdx.x; e<E; e+=blockDim.x)
            atomicAdd(&hist[((u32)dst[e])>>RSH], 1u);
    }
    __syncthreads();
    for(int b=threadIdx.x; b<B; b+=blockDim.x) blk_cnt[(size_t)sb*B + b] = hist[b];
}

// per-bucket exclusive scan over the SB per-block counts (one block per bucket)
__global__ __launch_bounds__(SB) void
colscan_kernel(u32* __restrict__ blk_cnt, int B, u32* __restrict__ tot){
    __shared__ u32 s[SB];
    int b = blockIdx.x, t = threadIdx.x;   // blockDim.x == SB
    u32 v = blk_cnt[(size_t)t*B + b];
    s[t] = v; __syncthreads();
    for(int off=1; off<SB; off<<=1){
        u32 x = (t>=off) ? s[t-off] : 0;
        __syncthreads();
        s[t] += x;
        __syncthreads();
    }
    blk_cnt[(size_t)t*B + b] = s[t] - v;     // exclusive
    if(t==SB-1) tot[b] = s[SB-1];
}

// exclusive scan of bucket totals -> bucket base offsets (single block, B <= 512)
__global__ void basescan_kernel(const u32* __restrict__ tot, u32* __restrict__ base, int B){
    __shared__ u32 s[256];
    int t = threadIdx.x;
    u32 v0 = (2*t   < B) ? tot[2*t]   : 0;
    u32 v1 = (2*t+1 < B) ? tot[2*t+1] : 0;
    u32 sum = v0 + v1;
    s[t] = sum; __syncthreads();
    for(int off=1; off<256; off<<=1){
        u32 x = (t>=off) ? s[t-off] : 0;
        __syncthreads();
        s[t] += x;
        __syncthreads();
    }
    u32 run = s[t] - sum;
    if(2*t   < B) base[2*t]   = run;
    if(2*t+1 < B) base[2*t+1] = run + v0;
    if(t==255) base[B] = s[255];     // == E
}

// pass 1: LDS-binned scatter into dst-bucket order (proven round-5 protocol)
__global__ __launch_bounds__(ST) void
scatter_kernel(const int* __restrict__ src, const int* __restrict__ dst,
               const float* __restrict__ ep, long long E, int B,
               const u32* __restrict__ blk_rel, const u32* __restrict__ base,
               uint2* __restrict__ edges){
    __shared__ uint2 bin[NBMAX][BINS];   // 32 KB
    __shared__ u32 cnt[NBMAX];
    __shared__ u32 gcur[NBMAX];
    const int sb = blockIdx.x, t = threadIdx.x;
    long long E4 = E >> 2;
    long long chunk = (E4 + SB - 1)/SB;
    long long i0 = (long long)sb*chunk;
    long long i1 = i0 + chunk; if(i1 > E4) i1 = E4;
    for(int b=t; b<B; b+=ST){ cnt[b]=0; gcur[b]=base[b]+blk_rel[(size_t)sb*B+b]; }
    __syncthreads();
    const int4*   s4=(const int4*)src;
    const int4*   d4=(const int4*)dst;
    const float4* w4=(const float4*)ep;
    for(long long it=i0; it<i1; it+=ST){
        long long i = it + t;
        bool valid = (i < i1);
        u32 bk[4]; u32 sl[4]; uint2 pl[4];
        if(valid){
            int4 s=s4[i]; int4 d=d4[i]; float4 w=w4[i];
            u32 dd;
            dd=(u32)d.x; bk[0]=dd>>RSH; pl[0]=make_uint2(((u32)s.x)|((dd&(RSZ-1))<<SRC_BITS), __float_as_uint(w.x));
            dd=(u32)d.y; bk[1]=dd>>RSH; pl[1]=make_uint2(((u32)s.y)|((dd&(RSZ-1))<<SRC_BITS), __float_as_uint(w.y));
            dd=(u32)d.z; bk[2]=dd>>RSH; pl[2]=make_uint2(((u32)s.z)|((dd&(RSZ-1))<<SRC_BITS), __float_as_uint(w.z));
            dd=(u32)d.w; bk[3]=dd>>RSH; pl[3]=make_uint2(((u32)s.w)|((dd&(RSZ-1))<<SRC_BITS), __float_as_uint(w.w));
            #pragma unroll
            for(int k=0;k<4;k++) sl[k]=atomicAdd(&cnt[bk[k]],1u);
        }
        __syncthreads();
        if(valid){
            #pragma unroll
            for(int k=0;k<4;k++){
                if(sl[k] < BINS) bin[bk[k]][sl[k]] = pl[k];
                else             edges[gcur[bk[k]] + sl[k]] = pl[k];
            }
        }
        __syncthreads();
        for(int b=t; b<B; b+=ST){
            u32 c = cnt[b];
            if(c >= BINS){
                u32 g = gcur[b];
                #pragma unroll
                for(int k2=0;k2<BINS;k2++) edges[g+k2] = bin[b][k2];
                gcur[b] = g + c;
                cnt[b]  = 0;
            }
        }
        __syncthreads();
    }
    if(sb==0){   // tail edges (E % 4)
        long long tb = E4<<2;
        int nt = (int)(E - tb);
        if(nt > 0){
            bool v = (t < nt);
            u32 bk0=0, sl0=0; uint2 pl0=make_uint2(0,0);
            if(v){
                u32 dd=(u32)dst[tb+t]; bk0=dd>>RSH;
                pl0=make_uint2(((u32)src[tb+t])|((dd&(RSZ-1))<<SRC_BITS), __float_as_uint(ep[tb+t]));
                sl0=atomicAdd(&cnt[bk0],1u);
            }
            __syncthreads();
            if(v){ if(sl0<BINS) bin[bk0][sl0]=pl0; else edges[gcur[bk0]+sl0]=pl0; }
            __syncthreads();
        }
    }
    for(int b=t; b<B; b+=ST){
        u32 c = cnt[b]; if(c > BINS) c = BINS;
        u32 g = gcur[b];
        for(u32 k2=0;k2<c;k2++) edges[g+k2] = bin[b][k2];
    }
}

// pass 2: per-bucket counting sort by dst_local -> exact CSR.
// Payload shrinks to u32 {src:19 | prob_q:13}; emits row_start from LDS scan.
// Same LDS-bin flush protocol (slot s <-> gcur[bin]+s invariant).
__global__ __launch_bounds__(1024) void
dstsort_kernel(const uint2* __restrict__ in, const u32* __restrict__ base,
               u32* __restrict__ csr, u32* __restrict__ row, int B){
    __shared__ u32 bin[RSZ][BINS];   // 32 KB
    __shared__ u32 hist[RSZ];
    __shared__ u32 sc[RSZ];
    __shared__ u32 cnt[RSZ];
    __shared__ u32 gcur[RSZ];
    int b = blockIdx.x, t = threadIdx.x;   // blockDim.x == 1024 == RSZ
    u32 e0 = base[b], e1 = base[b+1];
    hist[t] = 0;
    __syncthreads();
    for(u32 e=e0+t; e<e1; e+=1024)
        atomicAdd(&hist[in[e].x >> SRC_BITS], 1u);
    __syncthreads();
    u32 v = hist[t];
    sc[t] = v; __syncthreads();
    for(int off=1; off<RSZ; off<<=1){
        u32 x = (t>=off) ? sc[t-off] : 0;
        __syncthreads();
        sc[t] += x;
        __syncthreads();
    }
    u32 start = e0 + sc[t] - v;            // exclusive prefix
    row[(((size_t)b)<<RSH) + t] = start;
    if(b == B-1 && t == 0) row[((size_t)B)<<RSH] = e1;
    gcur[t] = start;
    cnt[t]  = 0;
    __syncthreads();
    for(u32 it=e0; it<e1; it+=1024){
        u32 e = it + t;
        bool valid = (e < e1);
        u32 bk=0, sl=0, pay=0;
        if(valid){
            uint2 pk = in[e];
            bk = pk.x >> SRC_BITS;
            u32 q = (u32)(__uint_as_float(pk.y)*QMAX + 0.5f);
            if(q > 8191u) q = 8191u;
            pay = (pk.x & SRC_MASK) | (q << SRC_BITS);
            sl = atomicAdd(&cnt[bk], 1u);
        }
        __syncthreads();
        if(valid){
            if(sl < BINS) bin[bk][sl] = pay;
            else          csr[gcur[bk] + sl] = pay;
        }
        __syncthreads();
        {   // thread t owns bin t
            u32 c = cnt[t];
            if(c >= BINS){
                u32 g = gcur[t];
                #pragma unroll
                for(int k=0;k<BINS;k++) csr[g+k] = bin[t][k];
                gcur[t] = g + c;
                cnt[t]  = 0;
            }
        }
        __syncthreads();
    }
    u32 c = cnt[t]; if(c > BINS) c = BINS;
    u32 g = gcur[t];
    for(u32 k=0;k<c;k++) csr[g+k] = bin[t][k];
}

// one step: one thread per node; contiguous CSR run, uint4 edge loads,
// register accumulation (no atomics, no LDS); fused node update; p ping-pong.
__global__ __launch_bounds__(256) void
step_csr(const u32* __restrict__ csr, const u32* __restrict__ row,
         const __half* __restrict__ pc, __half* __restrict__ pn,
         float* __restrict__ prod, const float* __restrict__ prior,
         float* __restrict__ out, int n, int final_step){
    int i = blockIdx.x*256 + threadIdx.x;
    if(i >= n) return;
    u32 s = row[i], e = row[i+1];
    float sum = 0.0f;
    u32 x = s;
    while(x < e && (x & 3u)){
        u32 w = csr[x++];
        sum += (float)(w >> SRC_BITS) * __half2float(pc[w & SRC_MASK]);
    }
    for(; x + 4 <= e; x += 4){
        uint4 w4 = *(const uint4*)&csr[x];
        sum += (float)(w4.x >> SRC_BITS) * __half2float(pc[w4.x & SRC_MASK]);
        sum += (float)(w4.y >> SRC_BITS) * __half2float(pc[w4.y & SRC_MASK]);
        sum += (float)(w4.z >> SRC_BITS) * __half2float(pc[w4.z & SRC_MASK]);
        sum += (float)(w4.w >> SRC_BITS) * __half2float(pc[w4.w & SRC_MASK]);
    }
    for(; x < e; ++x){
        u32 w = csr[x];
        sum += (float)(w >> SRC_BITS) * __half2float(pc[w & SRC_MASK]);
    }
    float a = sum * (1.0f/QMAX);
    float pr = prod[i];
    float np = pr * (1.0f - expf(-a));
    pr *= (1.0f - np);
    prod[i] = pr;
    pn[i] = __float2half_rn(np);
    if(final_step) out[i] = 1.0f - pr + prior[i];
}

// ---------------- fallback (round-1) kernels ----------------

__global__ void init_kernel(const float* __restrict__ prior, float* __restrict__ p,
                            float* __restrict__ prod, float* __restrict__ agg, int n){
    int i = blockIdx.x*blockDim.x + threadIdx.x;
    if(i<n){ p[i]=prior[i]; prod[i]=1.0f; agg[i]=0.0f; }
}

__global__ void edge_kernel(const int* __restrict__ src, const int* __restrict__ dst,
                            const float* __restrict__ ep, const float* __restrict__ p,
                            float* __restrict__ agg, int e4, int e_rem, long long e4base){
    int i = blockIdx.x*blockDim.x + threadIdx.x;
    if(i < e4){
        int4   s = ((const int4*)src)[i];
        int4   t = ((const int4*)dst)[i];
        float4 w = ((const float4*)ep)[i];
        atomicAdd(&agg[t.x], w.x * p[s.x]);
        atomicAdd(&agg[t.y], w.y * p[s.y]);
        atomicAdd(&agg[t.z], w.z * p[s.z]);
        atomicAdd(&agg[t.w], w.w * p[s.w]);
    }
    if(blockIdx.x==0 && threadIdx.x < e_rem){
        long long e = e4base + threadIdx.x;
        atomicAdd(&agg[dst[e]], ep[e]*p[src[e]]);
    }
}

__global__ void node_kernel(float* __restrict__ p, float* __restrict__ prod,
                            float* __restrict__ agg, const float* __restrict__ prior,
                            float* __restrict__ out, int n, int final_step){
    int i = blockIdx.x*blockDim.x + threadIdx.x;
    if(i<n){
        float a = agg[i]; agg[i]=0.0f;
        float pr_old = prod[i];
        float np = pr_old*(1.0f - expf(-a));
        float pr = pr_old*(1.0f - np);
        prod[i]=pr; p[i]=np;
        if(final_step) out[i] = 1.0f - pr + prior[i];
    }
}

// ---------------- launch ----------------

extern "C" void kernel_launch(void* const* d_in, const int* in_sizes, int n_in,
                              void* d_out, int out_size, void* d_ws, size_t ws_size,
                              hipStream_t stream){
    const float* prior = (const float*)d_in[0];
    const int*   eidx  = (const int*)d_in[1];
    const float* ep    = (const float*)d_in[2];

    const int n = in_sizes[0];
    const long long E = (long long)in_sizes[2];
    const int* src = eidx;
    const int* dst = eidx + E;
    float* out = (float*)d_out;

    const int B = (n + RSZ - 1) >> RSH;   // buckets (489 for n=500000)

    // ws layout
    size_t szNh  = align256((size_t)n * 2);              // fp16 p table (x2)
    size_t szN   = align256((size_t)n * 4);              // f32 prod
    size_t szB1  = align256((size_t)(B + 1) * 4);
    size_t szB   = align256((size_t)B * 4);
    size_t szCnt = align256((size_t)SB * B * 4);
    size_t szRow = align256((((size_t)B << RSH) + 1) * 4);
    size_t szE2  = align256((size_t)E * 8);              // pass-1 uint2 edges
    size_t szE1  = align256((size_t)E * 4);              // CSR u32 payloads

    size_t off_p0   = 0;
    size_t off_p1   = off_p0 + szNh;
    size_t off_prod = off_p1 + szNh;
    size_t off_base = off_prod + szN;
    size_t off_tot  = off_base + szB1;
    size_t off_cnt  = off_tot + szB;
    size_t off_row  = off_cnt + szCnt;
    size_t off_edge = off_row + szRow;
    size_t off_csr  = off_edge + szE2;
    size_t need     = off_csr + szE1;

    char* ws = (char*)d_ws;

    if(ws_size >= need && n < (1 << SRC_BITS) && B <= NBMAX){
        __half* p0   = (__half*)(ws + off_p0);
        __half* p1   = (__half*)(ws + off_p1);
        float*  prod = (float*) (ws + off_prod);
        u32*    base = (u32*)   (ws + off_base);
        u32*    tot  = (u32*)   (ws + off_tot);
        u32*    cnt  = (u32*)   (ws + off_cnt);
        u32*    row  = (u32*)   (ws + off_row);
        uint2*  edges= (uint2*) (ws + off_edge);
        u32*    csr  = (u32*)   (ws + off_csr);

        const int nb_n = (n + 255)/256;
        init_fast<<<nb_n, 256, 0, stream>>>(prior, p0, prod, n);
        hist_kernel<<<SB, HT, (size_t)B*4, stream>>>(dst, E, B, cnt);
        colscan_kernel<<<B, SB, 0, stream>>>(cnt, B, tot);
        basescan_kernel<<<1, 256, 0, stream>>>(tot, base, B);
        scatter_kernel<<<SB, ST, 0, stream>>>(src, dst, ep, E, B, cnt, base, edges);
        dstsort_kernel<<<B, 1024, 0, stream>>>(edges, base, csr, row, B);

        __half* pc = p0;
        __half* pn = p1;
        for(int step=0; step<NUM_STEPS; ++step){
            step_csr<<<nb_n, 256, 0, stream>>>(csr, row, pc, pn, prod, prior, out,
                                               n, step == NUM_STEPS-1 ? 1 : 0);
            __half* t2 = pc; pc = pn; pn = t2;
        }
    } else {
        // fallback: global-atomic version (round 1)
        float* p    = (float*)d_ws;
        float* prod = p + n;
        float* agg  = prod + n;
        const int nb_n = (n + 255)/256;
        init_kernel<<<nb_n, 256, 0, stream>>>(prior, p, prod, agg, n);
        const int e4 = (int)(E/4);
        const int e_rem = (int)(E%4);
        const long long e4base = (long long)e4*4;
        const int nb_e = (e4 + 255)/256;
        for(int step=0; step<NUM_STEPS; ++step){
            edge_kernel<<<nb_e, 256, 0, stream>>>(src, dst, ep, p, agg, e4, e_rem, e4base);
            node_kernel<<<nb_n, 256, 0, stream>>>(p, prod, agg, prior, out, n,
                                                  step == NUM_STEPS-1 ? 1 : 0);
        }
    }
}

// Round 10
// 1220.604 us; speedup vs baseline: 2.9487x; 1.2179x over previous
//
#include <hip/hip_runtime.h>
#include <hip/hip_fp16.h>

#define NUM_STEPS 5
typedef unsigned int u32;
typedef unsigned long long ull;
typedef int   i4nt __attribute__((ext_vector_type(4)));
typedef float f4nt __attribute__((ext_vector_type(4)));

// ---------------- fast path constants ----------------
#define RSH 10             // 1024 nodes per dst-bucket
#define RSZ 1024
#define SB  1024           // hist/scatter blocks (chunking MUST match between them)
#define HT  512            // hist threads
#define ST  512            // scatter threads
#define NBMAX 512          // max buckets supported by scatter LDS bins
#define BINS 8             // scatter bin slots (8 x 8B = 64B line)
#define SPLIT 2            // step blocks per bucket
#define SRC_BITS 19        // N=500000 < 2^19
#define SRC_MASK 0x7FFFFu

static inline size_t align256(size_t x){ return (x + 255) & ~(size_t)255; }

// ---------------- fast-path kernels ----------------

__global__ void init_fast(const float* __restrict__ prior, __half* __restrict__ p,
                          float* __restrict__ prod, int n){
    int i = blockIdx.x*blockDim.x + threadIdx.x;
    if(i<n){ p[i]=__float2half_rn(prior[i]); prod[i]=1.0f; }
}

// per-block histogram of edge targets into B buckets (nt int4 loads)
__global__ void hist_kernel(const int* __restrict__ dst, long long E, int B,
                            u32* __restrict__ blk_cnt){
    extern __shared__ u32 hist[];
    int sb = blockIdx.x;
    long long E4 = E >> 2;
    long long chunk = (E4 + SB - 1)/SB;
    long long i0 = (long long)sb*chunk;
    long long i1 = i0 + chunk; if(i1 > E4) i1 = E4;
    for(int b=threadIdx.x; b<B; b+=blockDim.x) hist[b]=0;
    __syncthreads();
    const i4nt* d4 = (const i4nt*)dst;
    for(long long i=i0+threadIdx.x; i<i1; i+=blockDim.x){
        i4nt d = __builtin_nontemporal_load(d4 + i);
        atomicAdd(&hist[((u32)d.x)>>RSH], 1u);
        atomicAdd(&hist[((u32)d.y)>>RSH], 1u);
        atomicAdd(&hist[((u32)d.z)>>RSH], 1u);
        atomicAdd(&hist[((u32)d.w)>>RSH], 1u);
    }
    if(sb==0){   // scalar tail (E % 4)
        for(long long e=(E4<<2)+threadIdx.x; e<E; e+=blockDim.x)
            atomicAdd(&hist[((u32)dst[e])>>RSH], 1u);
    }
    __syncthreads();
    for(int b=threadIdx.x; b<B; b+=blockDim.x) blk_cnt[(size_t)sb*B + b] = hist[b];
}

// per-bucket exclusive scan over the SB per-block counts (one block per bucket)
__global__ __launch_bounds__(SB) void
colscan_kernel(u32* __restrict__ blk_cnt, int B, u32* __restrict__ tot){
    __shared__ u32 s[SB];
    int b = blockIdx.x, t = threadIdx.x;   // blockDim.x == SB
    u32 v = blk_cnt[(size_t)t*B + b];
    s[t] = v; __syncthreads();
    for(int off=1; off<SB; off<<=1){
        u32 x = (t>=off) ? s[t-off] : 0;
        __syncthreads();
        s[t] += x;
        __syncthreads();
    }
    blk_cnt[(size_t)t*B + b] = s[t] - v;     // exclusive
    if(t==SB-1) tot[b] = s[SB-1];
}

// exclusive scan of bucket totals -> bucket base offsets (single block, B <= 512)
__global__ void basescan_kernel(const u32* __restrict__ tot, u32* __restrict__ base, int B){
    __shared__ u32 s[256];
    int t = threadIdx.x;
    u32 v0 = (2*t   < B) ? tot[2*t]   : 0;
    u32 v1 = (2*t+1 < B) ? tot[2*t+1] : 0;
    u32 sum = v0 + v1;
    s[t] = sum; __syncthreads();
    for(int off=1; off<256; off<<=1){
        u32 x = (t>=off) ? s[t-off] : 0;
        __syncthreads();
        s[t] += x;
        __syncthreads();
    }
    u32 run = s[t] - sum;
    if(2*t   < B) base[2*t]   = run;
    if(2*t+1 < B) base[2*t+1] = run + v0;
    if(t==255) base[B] = s[255];     // == E
}

// LDS-binned scatter into dst-bucket order; nt input streams protect L2 so
// partially-filled output lines stay resident until the 64B flush completes.
__global__ __launch_bounds__(ST) void
scatter_kernel(const int* __restrict__ src, const int* __restrict__ dst,
               const float* __restrict__ ep, long long E, int B,
               const u32* __restrict__ blk_rel, const u32* __restrict__ base,
               uint2* __restrict__ edges){
    __shared__ uint2 bin[NBMAX][BINS];   // 32 KB
    __shared__ u32 cnt[NBMAX];
    __shared__ u32 gcur[NBMAX];
    const int sb = blockIdx.x, t = threadIdx.x;
    long long E4 = E >> 2;
    long long chunk = (E4 + SB - 1)/SB;
    long long i0 = (long long)sb*chunk;
    long long i1 = i0 + chunk; if(i1 > E4) i1 = E4;
    for(int b=t; b<B; b+=ST){ cnt[b]=0; gcur[b]=base[b]+blk_rel[(size_t)sb*B+b]; }
    __syncthreads();
    const i4nt* s4=(const i4nt*)src;
    const i4nt* d4=(const i4nt*)dst;
    const f4nt* w4=(const f4nt*)ep;
    for(long long it=i0; it<i1; it+=ST){
        long long i = it + t;
        bool valid = (i < i1);
        u32 bk[4]; u32 sl[4]; uint2 pl[4];
        if(valid){
            i4nt s = __builtin_nontemporal_load(s4 + i);
            i4nt d = __builtin_nontemporal_load(d4 + i);
            f4nt w = __builtin_nontemporal_load(w4 + i);
            u32 dd;
            dd=(u32)d.x; bk[0]=dd>>RSH; pl[0]=make_uint2(((u32)s.x)|((dd&(RSZ-1))<<SRC_BITS), __float_as_uint(w.x));
            dd=(u32)d.y; bk[1]=dd>>RSH; pl[1]=make_uint2(((u32)s.y)|((dd&(RSZ-1))<<SRC_BITS), __float_as_uint(w.y));
            dd=(u32)d.z; bk[2]=dd>>RSH; pl[2]=make_uint2(((u32)s.z)|((dd&(RSZ-1))<<SRC_BITS), __float_as_uint(w.z));
            dd=(u32)d.w; bk[3]=dd>>RSH; pl[3]=make_uint2(((u32)s.w)|((dd&(RSZ-1))<<SRC_BITS), __float_as_uint(w.w));
            #pragma unroll
            for(int k=0;k<4;k++) sl[k]=atomicAdd(&cnt[bk[k]],1u);
        }
        __syncthreads();
        if(valid){
            #pragma unroll
            for(int k=0;k<4;k++){
                if(sl[k] < BINS) bin[bk[k]][sl[k]] = pl[k];
                else             edges[gcur[bk[k]] + sl[k]] = pl[k];
            }
        }
        __syncthreads();
        for(int b=t; b<B; b+=ST){
            u32 c = cnt[b];
            if(c >= BINS){
                u32 g = gcur[b];
                #pragma unroll
                for(int k2=0;k2<BINS;k2++) edges[g+k2] = bin[b][k2];
                gcur[b] = g + c;
                cnt[b]  = 0;
            }
        }
        __syncthreads();
    }
    if(sb==0){   // tail edges (E % 4)
        long long tb = E4<<2;
        int nt = (int)(E - tb);
        if(nt > 0){
            bool v = (t < nt);
            u32 bk0=0, sl0=0; uint2 pl0=make_uint2(0,0);
            if(v){
                u32 dd=(u32)dst[tb+t]; bk0=dd>>RSH;
                pl0=make_uint2(((u32)src[tb+t])|((dd&(RSZ-1))<<SRC_BITS), __float_as_uint(ep[tb+t]));
                sl0=atomicAdd(&cnt[bk0],1u);
            }
            __syncthreads();
            if(v){ if(sl0<BINS) bin[bk0][sl0]=pl0; else edges[gcur[bk0]+sl0]=pl0; }
            __syncthreads();
        }
    }
    for(int b=t; b<B; b+=ST){
        u32 c = cnt[b]; if(c > BINS) c = BINS;
        u32 g = gcur[b];
        for(u32 k2=0;k2<c;k2++) edges[g+k2] = bin[b][k2];
    }
}

// one step, part 1: SPLIT blocks per bucket; 4-deep ILP, NT edge stream
// (protects the fp16 p table in L2), LDS accumulation; nt f32 partial writes.
__global__ __launch_bounds__(512) void
step_kernel(const uint2* __restrict__ edges, const u32* __restrict__ base,
            const __half* __restrict__ p, float* __restrict__ pacc){
    __shared__ float acc[2][RSZ];
    int blk = blockIdx.x;
    int b   = blk >> 1;          // SPLIT == 2
    int part= blk & 1;
    int t   = threadIdx.x;
    for(int k=t; k<RSZ; k+=512){ acc[0][k]=0.0f; acc[1][k]=0.0f; }
    __syncthreads();
    u32 e0 = base[b], e1 = base[b+1];
    u32 cnt = e1 - e0;
    u32 s0 = e0 + (cnt*(u32)part)/SPLIT;
    u32 s1 = e0 + (cnt*(u32)(part+1))/SPLIT;
    int rep = t & 1;
    u32 n = s1 - s0;
    u32 m = n >> 11;             // full 2048-edge iterations (uniform across block)
    u32 eb = s0 + t;
    const ull* ed = (const ull*)edges;
    for(u32 it=0; it<m; ++it){
        ull r0 = __builtin_nontemporal_load(ed + eb);
        ull r1 = __builtin_nontemporal_load(ed + eb + 512);
        ull r2 = __builtin_nontemporal_load(ed + eb + 1024);
        ull r3 = __builtin_nontemporal_load(ed + eb + 1536);
        u32 x0=(u32)r0, x1=(u32)r1, x2=(u32)r2, x3=(u32)r3;
        float p0 = __half2float(p[x0 & SRC_MASK]);
        float p1 = __half2float(p[x1 & SRC_MASK]);
        float p2 = __half2float(p[x2 & SRC_MASK]);
        float p3 = __half2float(p[x3 & SRC_MASK]);
        atomicAdd(&acc[rep][x0 >> SRC_BITS], __uint_as_float((u32)(r0>>32))*p0);
        atomicAdd(&acc[rep][x1 >> SRC_BITS], __uint_as_float((u32)(r1>>32))*p1);
        atomicAdd(&acc[rep][x2 >> SRC_BITS], __uint_as_float((u32)(r2>>32))*p2);
        atomicAdd(&acc[rep][x3 >> SRC_BITS], __uint_as_float((u32)(r3>>32))*p3);
        eb += 2048;
    }
    for(u32 e=eb; e<s1; e+=512){
        ull r = __builtin_nontemporal_load(ed + e);
        u32 x = (u32)r;
        atomicAdd(&acc[rep][x >> SRC_BITS],
                  __uint_as_float((u32)(r>>32))*__half2float(p[x & SRC_MASK]));
    }
    __syncthreads();
    float* dstp = pacc + (size_t)blk * RSZ;
    for(int k=t; k<RSZ; k+=512)
        __builtin_nontemporal_store(acc[0][k] + acc[1][k], dstp + k);
}

// one step, part 2: combine partials, node update, in-place p overwrite
__global__ void combine_kernel(const float* __restrict__ pacc, __half* __restrict__ p,
                               float* __restrict__ prod, const float* __restrict__ prior,
                               float* __restrict__ out, int n, int final_step){
    int i = blockIdx.x*blockDim.x + threadIdx.x;
    if(i < n){
        int b = i >> RSH, k = i & (RSZ-1);
        float a = __builtin_nontemporal_load(&pacc[(size_t)(b*SPLIT    )*RSZ + k])
                + __builtin_nontemporal_load(&pacc[(size_t)(b*SPLIT + 1)*RSZ + k]);
        float pr_old = prod[i];
        float np = pr_old * (1.0f - expf(-a));
        float pr = pr_old * (1.0f - np);
        prod[i] = pr;
        p[i] = __float2half_rn(np);
        if(final_step) out[i] = 1.0f - pr + prior[i];
    }
}

// ---------------- fallback (round-1) kernels ----------------

__global__ void init_kernel(const float* __restrict__ prior, float* __restrict__ p,
                            float* __restrict__ prod, float* __restrict__ agg, int n){
    int i = blockIdx.x*blockDim.x + threadIdx.x;
    if(i<n){ p[i]=prior[i]; prod[i]=1.0f; agg[i]=0.0f; }
}

__global__ void edge_kernel(const int* __restrict__ src, const int* __restrict__ dst,
                            const float* __restrict__ ep, const float* __restrict__ p,
                            float* __restrict__ agg, int e4, int e_rem, long long e4base){
    int i = blockIdx.x*blockDim.x + threadIdx.x;
    if(i < e4){
        int4   s = ((const int4*)src)[i];
        int4   t = ((const int4*)dst)[i];
        float4 w = ((const float4*)ep)[i];
        atomicAdd(&agg[t.x], w.x * p[s.x]);
        atomicAdd(&agg[t.y], w.y * p[s.y]);
        atomicAdd(&agg[t.z], w.z * p[s.z]);
        atomicAdd(&agg[t.w], w.w * p[s.w]);
    }
    if(blockIdx.x==0 && threadIdx.x < e_rem){
        long long e = e4base + threadIdx.x;
        atomicAdd(&agg[dst[e]], ep[e]*p[src[e]]);
    }
}

__global__ void node_kernel(float* __restrict__ p, float* __restrict__ prod,
                            float* __restrict__ agg, const float* __restrict__ prior,
                            float* __restrict__ out, int n, int final_step){
    int i = blockIdx.x*blockDim.x + threadIdx.x;
    if(i<n){
        float a = agg[i]; agg[i]=0.0f;
        float pr_old = prod[i];
        float np = pr_old*(1.0f - expf(-a));
        float pr = pr_old*(1.0f - np);
        prod[i]=pr; p[i]=np;
        if(final_step) out[i] = 1.0f - pr + prior[i];
    }
}

// ---------------- launch ----------------

extern "C" void kernel_launch(void* const* d_in, const int* in_sizes, int n_in,
                              void* d_out, int out_size, void* d_ws, size_t ws_size,
                              hipStream_t stream){
    const float* prior = (const float*)d_in[0];
    const int*   eidx  = (const int*)d_in[1];
    const float* ep    = (const float*)d_in[2];

    const int n = in_sizes[0];
    const long long E = (long long)in_sizes[2];
    const int* src = eidx;
    const int* dst = eidx + E;
    float* out = (float*)d_out;

    const int B = (n + RSZ - 1) >> RSH;   // buckets (489 for n=500000)

    // ws layout
    size_t szNh  = align256((size_t)n * 2);              // fp16 p table
    size_t szN   = align256((size_t)n * 4);              // f32 prod
    size_t szB1  = align256((size_t)(B + 1) * 4);
    size_t szB   = align256((size_t)B * 4);
    size_t szCnt = align256((size_t)SB * B * 4);
    size_t szAcc = align256((size_t)SPLIT * B * RSZ * 4);
    size_t szE2  = align256((size_t)E * 8);

    size_t off_p    = 0;
    size_t off_prod = off_p + szNh;
    size_t off_base = off_prod + szN;
    size_t off_tot  = off_base + szB1;
    size_t off_cnt  = off_tot + szB;
    size_t off_acc  = off_cnt + szCnt;
    size_t off_edge = off_acc + szAcc;
    size_t need     = off_edge + szE2;

    char* ws = (char*)d_ws;

    if(ws_size >= need && n < (1 << SRC_BITS) && B <= NBMAX){
        __half* p    = (__half*)(ws + off_p);
        float*  prod = (float*) (ws + off_prod);
        u32*    base = (u32*)   (ws + off_base);
        u32*    tot  = (u32*)   (ws + off_tot);
        u32*    cnt  = (u32*)   (ws + off_cnt);
        float*  pacc = (float*) (ws + off_acc);
        uint2*  edges= (uint2*) (ws + off_edge);

        const int nb_n = (n + 255)/256;
        init_fast<<<nb_n, 256, 0, stream>>>(prior, p, prod, n);
        hist_kernel<<<SB, HT, (size_t)B*4, stream>>>(dst, E, B, cnt);
        colscan_kernel<<<B, SB, 0, stream>>>(cnt, B, tot);
        basescan_kernel<<<1, 256, 0, stream>>>(tot, base, B);
        scatter_kernel<<<SB, ST, 0, stream>>>(src, dst, ep, E, B, cnt, base, edges);

        for(int step=0; step<NUM_STEPS; ++step){
            step_kernel<<<B*SPLIT, 512, 0, stream>>>(edges, base, p, pacc);
            combine_kernel<<<nb_n, 256, 0, stream>>>(pacc, p, prod, prior, out, n,
                                                     step == NUM_STEPS-1 ? 1 : 0);
        }
    } else {
        // fallback: global-atomic version (round 1)
        float* p    = (float*)d_ws;
        float* prod = p + n;
        float* agg  = prod + n;
        const int nb_n = (n + 255)/256;
        init_kernel<<<nb_n, 256, 0, stream>>>(prior, p, prod, agg, n);
        const int e4 = (int)(E/4);
        const int e_rem = (int)(E%4);
        const long long e4base = (long long)e4*4;
        const int nb_e = (e4 + 255)/256;
        for(int step=0; step<NUM_STEPS; ++step){
            edge_kernel<<<nb_e, 256, 0, stream>>>(src, dst, ep, p, agg, e4, e_rem, e4base);
            node_kernel<<<nb_n, 256, 0, stream>>>(p, prod, agg, prior, out, n,
                                                  step == NUM_STEPS-1 ? 1 : 0);
        }
    }
}

// Round 11
// 1141.328 us; speedup vs baseline: 3.1535x; 1.0695x over previous
//
#include <hip/hip_runtime.h>
#include <hip/hip_fp16.h>

#define NUM_STEPS 5
typedef unsigned int u32;
typedef unsigned long long ull;

// ---------------- fast path constants ----------------
#define RSH 10             // 1024 nodes per dst-bucket
#define RSZ 1024
#define SB  512            // hist/scatter blocks (chunking MUST match between them)
#define HT  512            // hist threads
#define ST  512            // scatter threads
#define NBMAX 512          // max buckets supported by scatter LDS bins
#define BINS 8             // scatter bin slots (8 x 8B = 64B line)
#define SPLIT 4            // step blocks per bucket
#define SRC_BITS 19        // N=500000 < 2^19
#define SRC_MASK 0x7FFFFu

static inline size_t align256(size_t x){ return (x + 255) & ~(size_t)255; }

// ---------------- fast-path kernels ----------------

__global__ void init_fast(const float* __restrict__ prior, __half* __restrict__ p,
                          float* __restrict__ prod, int n){
    int i = blockIdx.x*blockDim.x + threadIdx.x;
    if(i<n){ p[i]=__float2half_rn(prior[i]); prod[i]=1.0f; }
}

// per-block histogram of edge targets into B buckets (int4-vectorized)
__global__ void hist_kernel(const int* __restrict__ dst, long long E, int B,
                            u32* __restrict__ blk_cnt){
    extern __shared__ u32 hist[];
    int sb = blockIdx.x;
    long long E4 = E >> 2;
    long long chunk = (E4 + SB - 1)/SB;
    long long i0 = (long long)sb*chunk;
    long long i1 = i0 + chunk; if(i1 > E4) i1 = E4;
    for(int b=threadIdx.x; b<B; b+=blockDim.x) hist[b]=0;
    __syncthreads();
    const int4* d4 = (const int4*)dst;
    for(long long i=i0+threadIdx.x; i<i1; i+=blockDim.x){
        int4 d = d4[i];
        atomicAdd(&hist[((u32)d.x)>>RSH], 1u);
        atomicAdd(&hist[((u32)d.y)>>RSH], 1u);
        atomicAdd(&hist[((u32)d.z)>>RSH], 1u);
        atomicAdd(&hist[((u32)d.w)>>RSH], 1u);
    }
    if(sb==0){   // scalar tail (E % 4)
        for(long long e=(E4<<2)+threadIdx.x; e<E; e+=blockDim.x)
            atomicAdd(&hist[((u32)dst[e])>>RSH], 1u);
    }
    __syncthreads();
    for(int b=threadIdx.x; b<B; b+=blockDim.x) blk_cnt[(size_t)sb*B + b] = hist[b];
}

// per-bucket exclusive scan over the SB per-block counts (one block per bucket)
__global__ __launch_bounds__(SB) void
colscan_kernel(u32* __restrict__ blk_cnt, int B, u32* __restrict__ tot){
    __shared__ u32 s[SB];
    int b = blockIdx.x, t = threadIdx.x;   // blockDim.x == SB
    u32 v = blk_cnt[(size_t)t*B + b];
    s[t] = v; __syncthreads();
    for(int off=1; off<SB; off<<=1){
        u32 x = (t>=off) ? s[t-off] : 0;
        __syncthreads();
        s[t] += x;
        __syncthreads();
    }
    blk_cnt[(size_t)t*B + b] = s[t] - v;     // exclusive
    if(t==SB-1) tot[b] = s[SB-1];
}

// exclusive scan of bucket totals -> bucket base offsets (single block, B <= 512)
__global__ void basescan_kernel(const u32* __restrict__ tot, u32* __restrict__ base, int B){
    __shared__ u32 s[256];
    int t = threadIdx.x;
    u32 v0 = (2*t   < B) ? tot[2*t]   : 0;
    u32 v1 = (2*t+1 < B) ? tot[2*t+1] : 0;
    u32 sum = v0 + v1;
    s[t] = sum; __syncthreads();
    for(int off=1; off<256; off<<=1){
        u32 x = (t>=off) ? s[t-off] : 0;
        __syncthreads();
        s[t] += x;
        __syncthreads();
    }
    u32 run = s[t] - sum;
    if(2*t   < B) base[2*t]   = run;
    if(2*t+1 < B) base[2*t+1] = run + v0;
    if(t==255) base[B] = s[255];     // == E
}

// LDS-binned scatter: proven round-5 protocol (SB=512, no nt)
__global__ __launch_bounds__(ST) void
scatter_kernel(const int* __restrict__ src, const int* __restrict__ dst,
               const float* __restrict__ ep, long long E, int B,
               const u32* __restrict__ blk_rel, const u32* __restrict__ base,
               uint2* __restrict__ edges){
    __shared__ uint2 bin[NBMAX][BINS];   // 32 KB
    __shared__ u32 cnt[NBMAX];
    __shared__ u32 gcur[NBMAX];
    const int sb = blockIdx.x, t = threadIdx.x;
    long long E4 = E >> 2;
    long long chunk = (E4 + SB - 1)/SB;
    long long i0 = (long long)sb*chunk;
    long long i1 = i0 + chunk; if(i1 > E4) i1 = E4;
    for(int b=t; b<B; b+=ST){ cnt[b]=0; gcur[b]=base[b]+blk_rel[(size_t)sb*B+b]; }
    __syncthreads();
    const int4*   s4=(const int4*)src;
    const int4*   d4=(const int4*)dst;
    const float4* w4=(const float4*)ep;
    for(long long it=i0; it<i1; it+=ST){
        long long i = it + t;
        bool valid = (i < i1);
        u32 bk[4]; u32 sl[4]; uint2 pl[4];
        if(valid){
            int4 s=s4[i]; int4 d=d4[i]; float4 w=w4[i];
            u32 dd;
            dd=(u32)d.x; bk[0]=dd>>RSH; pl[0]=make_uint2(((u32)s.x)|((dd&(RSZ-1))<<SRC_BITS), __float_as_uint(w.x));
            dd=(u32)d.y; bk[1]=dd>>RSH; pl[1]=make_uint2(((u32)s.y)|((dd&(RSZ-1))<<SRC_BITS), __float_as_uint(w.y));
            dd=(u32)d.z; bk[2]=dd>>RSH; pl[2]=make_uint2(((u32)s.z)|((dd&(RSZ-1))<<SRC_BITS), __float_as_uint(w.z));
            dd=(u32)d.w; bk[3]=dd>>RSH; pl[3]=make_uint2(((u32)s.w)|((dd&(RSZ-1))<<SRC_BITS), __float_as_uint(w.w));
            #pragma unroll
            for(int k=0;k<4;k++) sl[k]=atomicAdd(&cnt[bk[k]],1u);
        }
        __syncthreads();
        if(valid){
            #pragma unroll
            for(int k=0;k<4;k++){
                if(sl[k] < BINS) bin[bk[k]][sl[k]] = pl[k];
                else             edges[gcur[bk[k]] + sl[k]] = pl[k];
            }
        }
        __syncthreads();
        for(int b=t; b<B; b+=ST){
            u32 c = cnt[b];
            if(c >= BINS){
                u32 g = gcur[b];
                #pragma unroll
                for(int k2=0;k2<BINS;k2++) edges[g+k2] = bin[b][k2];
                gcur[b] = g + c;
                cnt[b]  = 0;
            }
        }
        __syncthreads();
    }
    if(sb==0){   // tail edges (E % 4)
        long long tb = E4<<2;
        int nt = (int)(E - tb);
        if(nt > 0){
            bool v = (t < nt);
            u32 bk0=0, sl0=0; uint2 pl0=make_uint2(0,0);
            if(v){
                u32 dd=(u32)dst[tb+t]; bk0=dd>>RSH;
                pl0=make_uint2(((u32)src[tb+t])|((dd&(RSZ-1))<<SRC_BITS), __float_as_uint(ep[tb+t]));
                sl0=atomicAdd(&cnt[bk0],1u);
            }
            __syncthreads();
            if(v){ if(sl0<BINS) bin[bk0][sl0]=pl0; else edges[gcur[bk0]+sl0]=pl0; }
            __syncthreads();
        }
    }
    for(int b=t; b<B; b+=ST){
        u32 c = cnt[b]; if(c > BINS) c = BINS;
        u32 g = gcur[b];
        for(u32 k2=0;k2<c;k2++) edges[g+k2] = bin[b][k2];
    }
}

// one step, part 1: SPLIT=4 blocks per bucket, 256 threads, 8-deep ILP
// (8 outstanding gathers per wave iteration), 2-replica LDS accumulation.
__global__ __launch_bounds__(256) void
step_kernel(const uint2* __restrict__ edges, const u32* __restrict__ base,
            const __half* __restrict__ p, float* __restrict__ pacc){
    __shared__ float acc[2][RSZ];      // 8 KB
    int blk = blockIdx.x;
    int b   = blk >> 2;                // SPLIT == 4
    int part= blk & 3;
    int t   = threadIdx.x;
    for(int k=t; k<RSZ; k+=256){ acc[0][k]=0.0f; acc[1][k]=0.0f; }
    __syncthreads();
    u32 e0 = base[b], e1 = base[b+1];
    u32 cnt = e1 - e0;
    u32 s0 = e0 + (cnt*(u32)part)/SPLIT;
    u32 s1 = e0 + (cnt*(u32)(part+1))/SPLIT;
    int rep = t & 1;
    u32 n = s1 - s0;
    u32 m = n >> 11;                   // full 2048-edge iterations (8 x 256)
    u32 eb = s0 + t;
    const ull* ed = (const ull*)edges;
    for(u32 it=0; it<m; ++it){
        ull r0 = ed[eb       ];
        ull r1 = ed[eb +  256];
        ull r2 = ed[eb +  512];
        ull r3 = ed[eb +  768];
        ull r4 = ed[eb + 1024];
        ull r5 = ed[eb + 1280];
        ull r6 = ed[eb + 1536];
        ull r7 = ed[eb + 1792];
        u32 x0=(u32)r0, x1=(u32)r1, x2=(u32)r2, x3=(u32)r3;
        u32 x4=(u32)r4, x5=(u32)r5, x6=(u32)r6, x7=(u32)r7;
        float p0 = __half2float(p[x0 & SRC_MASK]);
        float p1 = __half2float(p[x1 & SRC_MASK]);
        float p2 = __half2float(p[x2 & SRC_MASK]);
        float p3 = __half2float(p[x3 & SRC_MASK]);
        float p4 = __half2float(p[x4 & SRC_MASK]);
        float p5 = __half2float(p[x5 & SRC_MASK]);
        float p6 = __half2float(p[x6 & SRC_MASK]);
        float p7 = __half2float(p[x7 & SRC_MASK]);
        atomicAdd(&acc[rep][x0 >> SRC_BITS], __uint_as_float((u32)(r0>>32))*p0);
        atomicAdd(&acc[rep][x1 >> SRC_BITS], __uint_as_float((u32)(r1>>32))*p1);
        atomicAdd(&acc[rep][x2 >> SRC_BITS], __uint_as_float((u32)(r2>>32))*p2);
        atomicAdd(&acc[rep][x3 >> SRC_BITS], __uint_as_float((u32)(r3>>32))*p3);
        atomicAdd(&acc[rep][x4 >> SRC_BITS], __uint_as_float((u32)(r4>>32))*p4);
        atomicAdd(&acc[rep][x5 >> SRC_BITS], __uint_as_float((u32)(r5>>32))*p5);
        atomicAdd(&acc[rep][x6 >> SRC_BITS], __uint_as_float((u32)(r6>>32))*p6);
        atomicAdd(&acc[rep][x7 >> SRC_BITS], __uint_as_float((u32)(r7>>32))*p7);
        eb += 2048;
    }
    for(u32 e=eb; e<s1; e+=256){
        ull r = ed[e];
        u32 x = (u32)r;
        atomicAdd(&acc[rep][x >> SRC_BITS],
                  __uint_as_float((u32)(r>>32))*__half2float(p[x & SRC_MASK]));
    }
    __syncthreads();
    float* dstp = pacc + (size_t)blk * RSZ;
    for(int k=t; k<RSZ; k+=256) dstp[k] = acc[0][k] + acc[1][k];
}

// one step, part 2: combine SPLIT partials, node update, in-place p overwrite
__global__ void combine_kernel(const float* __restrict__ pacc, __half* __restrict__ p,
                               float* __restrict__ prod, const float* __restrict__ prior,
                               float* __restrict__ out, int n, int final_step){
    int i = blockIdx.x*blockDim.x + threadIdx.x;
    if(i < n){
        int b = i >> RSH, k = i & (RSZ-1);
        float a = 0.0f;
        #pragma unroll
        for(int q=0;q<SPLIT;q++)
            a += pacc[(size_t)(b*SPLIT + q)*RSZ + k];
        float pr_old = prod[i];
        float np = pr_old * (1.0f - expf(-a));
        float pr = pr_old * (1.0f - np);
        prod[i] = pr;
        p[i] = __float2half_rn(np);
        if(final_step) out[i] = 1.0f - pr + prior[i];
    }
}

// ---------------- fallback (round-1) kernels ----------------

__global__ void init_kernel(const float* __restrict__ prior, float* __restrict__ p,
                            float* __restrict__ prod, float* __restrict__ agg, int n){
    int i = blockIdx.x*blockDim.x + threadIdx.x;
    if(i<n){ p[i]=prior[i]; prod[i]=1.0f; agg[i]=0.0f; }
}

__global__ void edge_kernel(const int* __restrict__ src, const int* __restrict__ dst,
                            const float* __restrict__ ep, const float* __restrict__ p,
                            float* __restrict__ agg, int e4, int e_rem, long long e4base){
    int i = blockIdx.x*blockDim.x + threadIdx.x;
    if(i < e4){
        int4   s = ((const int4*)src)[i];
        int4   t = ((const int4*)dst)[i];
        float4 w = ((const float4*)ep)[i];
        atomicAdd(&agg[t.x], w.x * p[s.x]);
        atomicAdd(&agg[t.y], w.y * p[s.y]);
        atomicAdd(&agg[t.z], w.z * p[s.z]);
        atomicAdd(&agg[t.w], w.w * p[s.w]);
    }
    if(blockIdx.x==0 && threadIdx.x < e_rem){
        long long e = e4base + threadIdx.x;
        atomicAdd(&agg[dst[e]], ep[e]*p[src[e]]);
    }
}

__global__ void node_kernel(float* __restrict__ p, float* __restrict__ prod,
                            float* __restrict__ agg, const float* __restrict__ prior,
                            float* __restrict__ out, int n, int final_step){
    int i = blockIdx.x*blockDim.x + threadIdx.x;
    if(i<n){
        float a = agg[i]; agg[i]=0.0f;
        float pr_old = prod[i];
        float np = pr_old*(1.0f - expf(-a));
        float pr = pr_old*(1.0f - np);
        prod[i]=pr; p[i]=np;
        if(final_step) out[i] = 1.0f - pr + prior[i];
    }
}

// ---------------- launch ----------------

extern "C" void kernel_launch(void* const* d_in, const int* in_sizes, int n_in,
                              void* d_out, int out_size, void* d_ws, size_t ws_size,
                              hipStream_t stream){
    const float* prior = (const float*)d_in[0];
    const int*   eidx  = (const int*)d_in[1];
    const float* ep    = (const float*)d_in[2];

    const int n = in_sizes[0];
    const long long E = (long long)in_sizes[2];
    const int* src = eidx;
    const int* dst = eidx + E;
    float* out = (float*)d_out;

    const int B = (n + RSZ - 1) >> RSH;   // buckets (489 for n=500000)

    // ws layout
    size_t szNh  = align256((size_t)n * 2);              // fp16 p table
    size_t szN   = align256((size_t)n * 4);              // f32 prod
    size_t szB1  = align256((size_t)(B + 1) * 4);
    size_t szB   = align256((size_t)B * 4);
    size_t szCnt = align256((size_t)SB * B * 4);
    size_t szAcc = align256((size_t)SPLIT * B * RSZ * 4);
    size_t szE2  = align256((size_t)E * 8);

    size_t off_p    = 0;
    size_t off_prod = off_p + szNh;
    size_t off_base = off_prod + szN;
    size_t off_tot  = off_base + szB1;
    size_t off_cnt  = off_tot + szB;
    size_t off_acc  = off_cnt + szCnt;
    size_t off_edge = off_acc + szAcc;
    size_t need     = off_edge + szE2;

    char* ws = (char*)d_ws;

    if(ws_size >= need && n < (1 << SRC_BITS) && B <= NBMAX){
        __half* p    = (__half*)(ws + off_p);
        float*  prod = (float*) (ws + off_prod);
        u32*    base = (u32*)   (ws + off_base);
        u32*    tot  = (u32*)   (ws + off_tot);
        u32*    cnt  = (u32*)   (ws + off_cnt);
        float*  pacc = (float*) (ws + off_acc);
        uint2*  edges= (uint2*) (ws + off_edge);

        const int nb_n = (n + 255)/256;
        init_fast<<<nb_n, 256, 0, stream>>>(prior, p, prod, n);
        hist_kernel<<<SB, HT, (size_t)B*4, stream>>>(dst, E, B, cnt);
        colscan_kernel<<<B, SB, 0, stream>>>(cnt, B, tot);
        basescan_kernel<<<1, 256, 0, stream>>>(tot, base, B);
        scatter_kernel<<<SB, ST, 0, stream>>>(src, dst, ep, E, B, cnt, base, edges);

        for(int step=0; step<NUM_STEPS; ++step){
            step_kernel<<<B*SPLIT, 256, 0, stream>>>(edges, base, p, pacc);
            combine_kernel<<<nb_n, 256, 0, stream>>>(pacc, p, prod, prior, out, n,
                                                     step == NUM_STEPS-1 ? 1 : 0);
        }
    } else {
        // fallback: global-atomic version (round 1)
        float* p    = (float*)d_ws;
        float* prod = p + n;
        float* agg  = prod + n;
        const int nb_n = (n + 255)/256;
        init_kernel<<<nb_n, 256, 0, stream>>>(prior, p, prod, agg, n);
        const int e4 = (int)(E/4);
        const int e_rem = (int)(E%4);
        const long long e4base = (long long)e4*4;
        const int nb_e = (e4 + 255)/256;
        for(int step=0; step<NUM_STEPS; ++step){
            edge_kernel<<<nb_e, 256, 0, stream>>>(src, dst, ep, p, agg, e4, e_rem, e4base);
            node_kernel<<<nb_n, 256, 0, stream>>>(p, prod, agg, prior, out, n,
                                                  step == NUM_STEPS-1 ? 1 : 0);
        }
    }
}